// Round 7
// baseline (536.738 us; speedup 1.0000x reference)
//
#include <hip/hip_runtime.h>
#include <hip/hip_cooperative_groups.h>

namespace cg = cooperative_groups;

#define N_NODES 50000
#define N_EDGES 800000
#define IN_SIZE 128
#define OUT_SIZE 64
#define BIN_CAP 64   // Poisson(16) => P(>=64) ~ 2e-18

// GEMM tiling
#define BM 128
#define KC 32
#define KPAD 36      // xs row stride (2-way bank alias only = free)

#define NGEMM ((N_NODES + BM - 1) / BM)      // 391 gemm tiles
#define NBIN  ((N_EDGES + 1023) / 1024)      // 782 bin chunks (1024 edges each)
#define NTASK (NGEMM + NBIN)

// =========================================================================
// Cooperative kernel: phase0 zero cnt -> sync -> phase1 {gemm|bin} dynamic
// tasks -> sync -> phase2 per-row gather-reduce (+bias).
// wt LDS layout: wt[kc][c][32] with XOR-swizzled k4 groups so the wave's 16
// distinct c-rows map to 8 distinct banks (2-way alias = free on CDNA4).
// =========================================================================
__global__ __launch_bounds__(256, 3) void gcn_coop(
        const float* __restrict__ x, const float* __restrict__ w,
        const int* __restrict__ rows, const int* __restrict__ cols,
        const float* __restrict__ vals, const float* __restrict__ bias,
        float* __restrict__ support, int* __restrict__ cnt,
        int2* __restrict__ pay, int* __restrict__ task,
        float* __restrict__ out) {
    __shared__ float xs[BM][KPAD];           // 18.4 KB
    __shared__ float wt[4][OUT_SIZE][32];    // 32.0 KB, swizzled
    __shared__ int task_s;
    const int tid = threadIdx.x;
    cg::grid_group grid = cg::this_grid();

    // ---------------- phase 0: zero counters ----------------
    for (int i = blockIdx.x * 256 + tid; i < N_NODES; i += gridDim.x * 256)
        cnt[i] = 0;
    if (blockIdx.x == 0 && tid == 0) *task = 0;
    grid.sync();

    // ---------------- phase 1: dynamic gemm/bin tasks ----------------
    bool wt_loaded = false;
    for (;;) {
        if (tid == 0) task_s = atomicAdd(task, 1);
        __syncthreads();
        const int t = task_s;
        __syncthreads();                     // protect task_s before next write
        if (t >= NTASK) break;

        if (t < NGEMM) {
            // ---------- GEMM tile ----------
            const int row0 = t * BM;
            if (!wt_loaded) {
                wt_loaded = true;
                #pragma unroll
                for (int i = 0; i < 8; ++i) {
                    const int f  = tid + 256 * i;        // f < 2048
                    const int k  = f >> 4;               // 0..127
                    const int c0 = (f & 15) << 2;        // 0..60
                    const float4 wv = ((const float4*)w)[f];
                    const int kk = k & 31;
                    const int sw = (((kk >> 2) ^ (f & 7)) << 2) + (kk & 3);
                    wt[k >> 5][c0 + 0][sw] = wv.x;
                    wt[k >> 5][c0 + 1][sw] = wv.y;
                    wt[k >> 5][c0 + 2][sw] = wv.z;
                    wt[k >> 5][c0 + 3][sw] = wv.w;
                }
            }
            float4 xreg[4];
            #pragma unroll
            for (int i = 0; i < 4; ++i) {
                const int f = tid + 256 * i;             // row=f>>3, koff=(f&7)*4
                int r = row0 + (f >> 3);
                if (r >= N_NODES) r = N_NODES - 1;
                xreg[i] = *(const float4*)(x + (long)r * IN_SIZE + ((f & 7) << 2));
            }
            const int rg = tid & 15;
            const int c0r = (tid >> 4) << 2;
            const int m7  = (tid >> 4) & 7;
            float4 acc[8];
            #pragma unroll
            for (int i = 0; i < 8; ++i) acc[i] = make_float4(0.f, 0.f, 0.f, 0.f);

            for (int kc = 0; kc < 4; ++kc) {
                __syncthreads();
                #pragma unroll
                for (int i = 0; i < 4; ++i) {
                    const int f = tid + 256 * i;
                    *(float4*)&xs[f >> 3][(f & 7) << 2] = xreg[i];
                }
                __syncthreads();
                if (kc < 3) {
                    #pragma unroll
                    for (int i = 0; i < 4; ++i) {
                        const int f = tid + 256 * i;
                        int r = row0 + (f >> 3);
                        if (r >= N_NODES) r = N_NODES - 1;
                        xreg[i] = *(const float4*)(x + (long)r * IN_SIZE + (kc + 1) * KC + ((f & 7) << 2));
                    }
                }
                #pragma unroll
                for (int k4 = 0; k4 < 8; ++k4) {
                    const int so = (k4 ^ m7) << 2;
                    const float4 w0 = *(const float4*)&wt[kc][c0r + 0][so];
                    const float4 w1 = *(const float4*)&wt[kc][c0r + 1][so];
                    const float4 w2 = *(const float4*)&wt[kc][c0r + 2][so];
                    const float4 w3 = *(const float4*)&wt[kc][c0r + 3][so];
                    #pragma unroll
                    for (int i = 0; i < 8; ++i) {
                        const float4 xv = *(const float4*)&xs[rg + (i << 4)][k4 << 2];
                        acc[i].x += xv.x * w0.x + xv.y * w0.y + xv.z * w0.z + xv.w * w0.w;
                        acc[i].y += xv.x * w1.x + xv.y * w1.y + xv.z * w1.z + xv.w * w1.w;
                        acc[i].z += xv.x * w2.x + xv.y * w2.y + xv.z * w2.z + xv.w * w2.w;
                        acc[i].w += xv.x * w3.x + xv.y * w3.y + xv.z * w3.z + xv.w * w3.w;
                    }
                }
            }
            #pragma unroll
            for (int i = 0; i < 8; ++i) {
                const int r = row0 + rg + (i << 4);
                if (r < N_NODES)
                    *(float4*)(support + (long)r * OUT_SIZE + c0r) = acc[i];
            }
            __syncthreads();   // xs reuse safety before next task
        } else {
            // ---------- BIN chunk ----------
            const int i  = (t - NGEMM) * 256 + tid;
            const int e0 = i * 4;
            if (e0 + 4 <= N_EDGES) {
                const int4   r4 = ((const int4*)rows)[i];
                const int4   c4 = ((const int4*)cols)[i];
                const float4 v4 = ((const float4*)vals)[i];
                int s;
                s = atomicAdd(&cnt[r4.x], 1); if (s < BIN_CAP) pay[r4.x * BIN_CAP + s] = make_int2(c4.x, __float_as_int(v4.x));
                s = atomicAdd(&cnt[r4.y], 1); if (s < BIN_CAP) pay[r4.y * BIN_CAP + s] = make_int2(c4.y, __float_as_int(v4.y));
                s = atomicAdd(&cnt[r4.z], 1); if (s < BIN_CAP) pay[r4.z * BIN_CAP + s] = make_int2(c4.z, __float_as_int(v4.z));
                s = atomicAdd(&cnt[r4.w], 1); if (s < BIN_CAP) pay[r4.w * BIN_CAP + s] = make_int2(c4.w, __float_as_int(v4.w));
            } else {
                for (int e = e0; e < N_EDGES; ++e) {
                    const int r = rows[e];
                    const int s = atomicAdd(&cnt[r], 1);
                    if (s < BIN_CAP) pay[r * BIN_CAP + s] = make_int2(cols[e], __float_as_int(vals[e]));
                }
            }
        }
    }

    __threadfence();
    grid.sync();

    // ---------------- phase 2: per-row gather-reduce ----------------
    const int lane = tid & 63;
    for (int g = blockIdx.x; g < (N_NODES + 3) / 4; g += gridDim.x) {
        const int row = g * 4 + (tid >> 6);
        if (row >= N_NODES) continue;
        const int n = min(cnt[row], BIN_CAP);
        int2 p = make_int2(0, 0);
        if (lane < n) p = pay[(long)row * BIN_CAP + lane];
        float acc = bias[lane];
        int k = 0;
        for (; k + 8 <= n; k += 8) {
            float gg[8], vv[8];
            #pragma unroll
            for (int j = 0; j < 8; ++j) {
                const int c = __shfl(p.x, k + j, 64);
                vv[j] = __int_as_float(__shfl(p.y, k + j, 64));
                gg[j] = support[(long)c * OUT_SIZE + lane];
            }
            #pragma unroll
            for (int j = 0; j < 8; ++j) acc += gg[j] * vv[j];
        }
        for (; k < n; ++k) {
            const int c = __shfl(p.x, k, 64);
            const float v = __int_as_float(__shfl(p.y, k, 64));
            acc += support[(long)c * OUT_SIZE + lane] * v;
        }
        out[(long)row * OUT_SIZE + lane] = acc;
    }
}

// =========================================================================
// Fallback path (R6 structure): memset + fused_gemm_bin + reduce_rows_pay
// =========================================================================
#define G_GEMM NGEMM
#define G_BIN  ((N_EDGES / 4 + 255) / 256)

__global__ __launch_bounds__(256) void fused_gemm_bin(
        const float* __restrict__ x, const float* __restrict__ w,
        float* __restrict__ support,
        const int* __restrict__ rows, const int* __restrict__ cols,
        const float* __restrict__ vals,
        int* __restrict__ cnt, int2* __restrict__ pay) {
    __shared__ float xs[BM][KPAD];
    __shared__ float wt[4][OUT_SIZE][32];
    const int tid = threadIdx.x;

    if (blockIdx.x < G_GEMM) {
        const int row0 = blockIdx.x * BM;
        #pragma unroll
        for (int i = 0; i < 8; ++i) {
            const int f  = tid + 256 * i;
            const int k  = f >> 4;
            const int c0 = (f & 15) << 2;
            const float4 wv = ((const float4*)w)[f];
            const int kk = k & 31;
            const int sw = (((kk >> 2) ^ (f & 7)) << 2) + (kk & 3);
            wt[k >> 5][c0 + 0][sw] = wv.x;
            wt[k >> 5][c0 + 1][sw] = wv.y;
            wt[k >> 5][c0 + 2][sw] = wv.z;
            wt[k >> 5][c0 + 3][sw] = wv.w;
        }
        float4 xreg[4];
        #pragma unroll
        for (int i = 0; i < 4; ++i) {
            const int f = tid + 256 * i;
            int r = row0 + (f >> 3);
            if (r >= N_NODES) r = N_NODES - 1;
            xreg[i] = *(const float4*)(x + (long)r * IN_SIZE + ((f & 7) << 2));
        }
        const int rg = tid & 15;
        const int c0r = (tid >> 4) << 2;
        const int m7  = (tid >> 4) & 7;
        float4 acc[8];
        #pragma unroll
        for (int i = 0; i < 8; ++i) acc[i] = make_float4(0.f, 0.f, 0.f, 0.f);
        for (int kc = 0; kc < 4; ++kc) {
            __syncthreads();
            #pragma unroll
            for (int i = 0; i < 4; ++i) {
                const int f = tid + 256 * i;
                *(float4*)&xs[f >> 3][(f & 7) << 2] = xreg[i];
            }
            __syncthreads();
            if (kc < 3) {
                #pragma unroll
                for (int i = 0; i < 4; ++i) {
                    const int f = tid + 256 * i;
                    int r = row0 + (f >> 3);
                    if (r >= N_NODES) r = N_NODES - 1;
                    xreg[i] = *(const float4*)(x + (long)r * IN_SIZE + (kc + 1) * KC + ((f & 7) << 2));
                }
            }
            #pragma unroll
            for (int k4 = 0; k4 < 8; ++k4) {
                const int so = (k4 ^ m7) << 2;
                const float4 w0 = *(const float4*)&wt[kc][c0r + 0][so];
                const float4 w1 = *(const float4*)&wt[kc][c0r + 1][so];
                const float4 w2 = *(const float4*)&wt[kc][c0r + 2][so];
                const float4 w3 = *(const float4*)&wt[kc][c0r + 3][so];
                #pragma unroll
                for (int i = 0; i < 8; ++i) {
                    const float4 xv = *(const float4*)&xs[rg + (i << 4)][k4 << 2];
                    acc[i].x += xv.x * w0.x + xv.y * w0.y + xv.z * w0.z + xv.w * w0.w;
                    acc[i].y += xv.x * w1.x + xv.y * w1.y + xv.z * w1.z + xv.w * w1.w;
                    acc[i].z += xv.x * w2.x + xv.y * w2.y + xv.z * w2.z + xv.w * w2.w;
                    acc[i].w += xv.x * w3.x + xv.y * w3.y + xv.z * w3.z + xv.w * w3.w;
                }
            }
        }
        #pragma unroll
        for (int i = 0; i < 8; ++i) {
            const int r = row0 + rg + (i << 4);
            if (r < N_NODES)
                *(float4*)(support + (long)r * OUT_SIZE + c0r) = acc[i];
        }
    } else {
        const int i  = (blockIdx.x - G_GEMM) * 256 + tid;
        const int e0 = i * 4;
        if (e0 + 4 <= N_EDGES) {
            const int4   r4 = ((const int4*)rows)[i];
            const int4   c4 = ((const int4*)cols)[i];
            const float4 v4 = ((const float4*)vals)[i];
            int s;
            s = atomicAdd(&cnt[r4.x], 1); if (s < BIN_CAP) pay[r4.x * BIN_CAP + s] = make_int2(c4.x, __float_as_int(v4.x));
            s = atomicAdd(&cnt[r4.y], 1); if (s < BIN_CAP) pay[r4.y * BIN_CAP + s] = make_int2(c4.y, __float_as_int(v4.y));
            s = atomicAdd(&cnt[r4.z], 1); if (s < BIN_CAP) pay[r4.z * BIN_CAP + s] = make_int2(c4.z, __float_as_int(v4.z));
            s = atomicAdd(&cnt[r4.w], 1); if (s < BIN_CAP) pay[r4.w * BIN_CAP + s] = make_int2(c4.w, __float_as_int(v4.w));
        } else {
            for (int e = e0; e < N_EDGES; ++e) {
                const int r = rows[e];
                const int s = atomicAdd(&cnt[r], 1);
                if (s < BIN_CAP) pay[r * BIN_CAP + s] = make_int2(cols[e], __float_as_int(vals[e]));
            }
        }
    }
}

__global__ __launch_bounds__(256) void reduce_rows_pay(const float* __restrict__ support,
                                                       const int* __restrict__ cnt,
                                                       const int2* __restrict__ pay,
                                                       const float* __restrict__ bias,
                                                       float* __restrict__ out) {
    const int tid  = threadIdx.x;
    const int lane = tid & 63;
    const int row  = blockIdx.x * 4 + (tid >> 6);
    if (row >= N_NODES) return;
    const int n = min(cnt[row], BIN_CAP);
    int2 p = make_int2(0, 0);
    if (lane < n) p = pay[(long)row * BIN_CAP + lane];
    float acc = bias[lane];
    int k = 0;
    for (; k + 8 <= n; k += 8) {
        float g[8], v[8];
        #pragma unroll
        for (int j = 0; j < 8; ++j) {
            const int c = __shfl(p.x, k + j, 64);
            v[j] = __int_as_float(__shfl(p.y, k + j, 64));
            g[j] = support[(long)c * OUT_SIZE + lane];
        }
        #pragma unroll
        for (int j = 0; j < 8; ++j) acc += g[j] * v[j];
    }
    for (; k < n; ++k) {
        const int c = __shfl(p.x, k, 64);
        const float v = __int_as_float(__shfl(p.y, k, 64));
        acc += support[(long)c * OUT_SIZE + lane] * v;
    }
    out[(long)row * OUT_SIZE + lane] = acc;
}

// =========================================================================
extern "C" void kernel_launch(void* const* d_in, const int* in_sizes, int n_in,
                              void* d_out, int out_size, void* d_ws, size_t ws_size,
                              hipStream_t stream) {
    const float* x      = (const float*)d_in[0];
    const int*   rows   = (const int*)d_in[1];
    const int*   cols   = (const int*)d_in[2];
    const float* vals   = (const float*)d_in[3];
    const float* weight = (const float*)d_in[4];
    const float* bias   = (const float*)d_in[5];
    float*       out    = (float*)d_out;

    const size_t support_bytes = (size_t)N_NODES * OUT_SIZE * sizeof(float); // 12.8 MB
    const size_t cnt_bytes     = (size_t)N_NODES * sizeof(int);              // 0.2 MB
    const size_t pay_bytes     = (size_t)N_NODES * BIN_CAP * sizeof(int2);   // 25.6 MB

    float* support = (float*)d_ws;
    int*   cnt     = (int*)((char*)d_ws + support_bytes);
    int2*  pay     = (int2*)((char*)d_ws + support_bytes + cnt_bytes);
    int*   task    = (int*)((char*)d_ws + support_bytes + cnt_bytes + pay_bytes);

    if (ws_size >= support_bytes + cnt_bytes + pay_bytes + 256) {
        // ---- cooperative single-dispatch path ----
        int occ = 0;
        if (hipOccupancyMaxActiveBlocksPerMultiprocessor(&occ, gcn_coop, 256, 0)
                == hipSuccess && occ > 0) {
            if (occ > 3) occ = 3;
            int nblocks = occ * 256;            // 256 CUs on MI355X
            void* args[] = {(void*)&x, (void*)&weight, (void*)&rows, (void*)&cols,
                            (void*)&vals, (void*)&bias, (void*)&support, (void*)&cnt,
                            (void*)&pay, (void*)&task, (void*)&out};
            if (hipLaunchCooperativeKernel((void*)gcn_coop, dim3(nblocks), dim3(256),
                                           args, 0, stream) == hipSuccess)
                return;
        }
        // ---- fallback: R6 three-dispatch path ----
        hipMemsetAsync(cnt, 0, cnt_bytes, stream);
        fused_gemm_bin<<<G_GEMM + G_BIN, 256, 0, stream>>>(x, weight, support,
                                                           rows, cols, vals, cnt, pay);
        reduce_rows_pay<<<(N_NODES + 3) / 4, 256, 0, stream>>>(support, cnt, pay, bias, out);
        return;
    }

    // ws too small for payload path: do everything with fused + atomics on out
    hipMemsetAsync(cnt, 0, cnt_bytes, stream);
    fused_gemm_bin<<<G_GEMM + G_BIN, 256, 0, stream>>>(x, weight, support,
                                                       rows, cols, vals, cnt, pay);
    reduce_rows_pay<<<(N_NODES + 3) / 4, 256, 0, stream>>>(support, cnt, pay, bias, out);
}

// Round 8
// 105.468 us; speedup vs baseline: 5.0891x; 5.0891x over previous
//
#include <hip/hip_runtime.h>
#include <hip/hip_cooperative_groups.h>

namespace cg = cooperative_groups;

#define N_NODES 50000
#define N_EDGES 800000
#define IN_SIZE 128
#define OUT_SIZE 64
#define BIN_CAP 64   // Poisson(16) => P(>=64) ~ 2e-18

// GEMM tiling
#define BM 128
#define KC 32
#define KPAD 36      // xs row stride (2-way bank alias only = free)

#define NGEMM ((N_NODES + BM - 1) / BM)      // 391 gemm tiles
#define NBIN  ((N_EDGES + 1023) / 1024)      // 782 bin chunks (1024 edges each)
#define NTASK (NGEMM + NBIN)

// =========================================================================
// Cooperative kernel: phase0 zero cnt -> sync -> phase1 {gemm|bin} dynamic
// tasks -> sync -> phase2 per-row gather-reduce (+bias).
// NOTE: NO min-waves arg in launch_bounds — R7 proved that capping VGPRs to
// 84 spills the 32-VGPR accumulator tile (1.2 GB scratch traffic, 6x slow).
// =========================================================================
__global__ __launch_bounds__(256) void gcn_coop(
        const float* __restrict__ x, const float* __restrict__ w,
        const int* __restrict__ rows, const int* __restrict__ cols,
        const float* __restrict__ vals, const float* __restrict__ bias,
        float* __restrict__ support, int* __restrict__ cnt,
        int2* __restrict__ pay, int* __restrict__ task,
        float* __restrict__ out) {
    __shared__ float xs[BM][KPAD];           // 18.4 KB
    __shared__ float wt[4][OUT_SIZE][32];    // 32.0 KB, swizzled
    __shared__ int task_s;
    const int tid = threadIdx.x;
    cg::grid_group grid = cg::this_grid();

    // ---------------- phase 0: zero counters ----------------
    for (int i = blockIdx.x * 256 + tid; i < N_NODES; i += gridDim.x * 256)
        cnt[i] = 0;
    if (blockIdx.x == 0 && tid == 0) *task = 0;
    grid.sync();

    // ---------------- phase 1: dynamic gemm/bin tasks ----------------
    bool wt_loaded = false;
    for (;;) {
        if (tid == 0) task_s = atomicAdd(task, 1);
        __syncthreads();
        const int t = task_s;
        __syncthreads();                     // protect task_s before next write
        if (t >= NTASK) break;

        if (t < NGEMM) {
            // ---------- GEMM tile ----------
            const int row0 = t * BM;
            if (!wt_loaded) {
                wt_loaded = true;
                #pragma unroll
                for (int i = 0; i < 8; ++i) {
                    const int f  = tid + 256 * i;        // f < 2048
                    const int k  = f >> 4;               // 0..127
                    const int c0 = (f & 15) << 2;        // 0..60
                    const float4 wv = ((const float4*)w)[f];
                    const int kk = k & 31;
                    const int sw = (((kk >> 2) ^ (f & 7)) << 2) + (kk & 3);
                    wt[k >> 5][c0 + 0][sw] = wv.x;
                    wt[k >> 5][c0 + 1][sw] = wv.y;
                    wt[k >> 5][c0 + 2][sw] = wv.z;
                    wt[k >> 5][c0 + 3][sw] = wv.w;
                }
            }
            float4 xreg[4];
            #pragma unroll
            for (int i = 0; i < 4; ++i) {
                const int f = tid + 256 * i;             // row=f>>3, koff=(f&7)*4
                int r = row0 + (f >> 3);
                if (r >= N_NODES) r = N_NODES - 1;
                xreg[i] = *(const float4*)(x + (long)r * IN_SIZE + ((f & 7) << 2));
            }
            const int rg = tid & 15;
            const int c0r = (tid >> 4) << 2;
            const int m7  = (tid >> 4) & 7;
            float4 acc[8];
            #pragma unroll
            for (int i = 0; i < 8; ++i) acc[i] = make_float4(0.f, 0.f, 0.f, 0.f);

            for (int kc = 0; kc < 4; ++kc) {
                __syncthreads();
                #pragma unroll
                for (int i = 0; i < 4; ++i) {
                    const int f = tid + 256 * i;
                    *(float4*)&xs[f >> 3][(f & 7) << 2] = xreg[i];
                }
                __syncthreads();
                if (kc < 3) {
                    #pragma unroll
                    for (int i = 0; i < 4; ++i) {
                        const int f = tid + 256 * i;
                        int r = row0 + (f >> 3);
                        if (r >= N_NODES) r = N_NODES - 1;
                        xreg[i] = *(const float4*)(x + (long)r * IN_SIZE + (kc + 1) * KC + ((f & 7) << 2));
                    }
                }
                #pragma unroll
                for (int k4 = 0; k4 < 8; ++k4) {
                    const int so = (k4 ^ m7) << 2;
                    const float4 w0 = *(const float4*)&wt[kc][c0r + 0][so];
                    const float4 w1 = *(const float4*)&wt[kc][c0r + 1][so];
                    const float4 w2 = *(const float4*)&wt[kc][c0r + 2][so];
                    const float4 w3 = *(const float4*)&wt[kc][c0r + 3][so];
                    #pragma unroll
                    for (int i = 0; i < 8; ++i) {
                        const float4 xv = *(const float4*)&xs[rg + (i << 4)][k4 << 2];
                        acc[i].x += xv.x * w0.x + xv.y * w0.y + xv.z * w0.z + xv.w * w0.w;
                        acc[i].y += xv.x * w1.x + xv.y * w1.y + xv.z * w1.z + xv.w * w1.w;
                        acc[i].z += xv.x * w2.x + xv.y * w2.y + xv.z * w2.z + xv.w * w2.w;
                        acc[i].w += xv.x * w3.x + xv.y * w3.y + xv.z * w3.z + xv.w * w3.w;
                    }
                }
            }
            #pragma unroll
            for (int i = 0; i < 8; ++i) {
                const int r = row0 + rg + (i << 4);
                if (r < N_NODES)
                    *(float4*)(support + (long)r * OUT_SIZE + c0r) = acc[i];
            }
            __syncthreads();   // xs reuse safety before next task
        } else {
            // ---------- BIN chunk ----------
            const int i  = (t - NGEMM) * 256 + tid;
            const int e0 = i * 4;
            if (e0 + 4 <= N_EDGES) {
                const int4   r4 = ((const int4*)rows)[i];
                const int4   c4 = ((const int4*)cols)[i];
                const float4 v4 = ((const float4*)vals)[i];
                int s;
                s = atomicAdd(&cnt[r4.x], 1); if (s < BIN_CAP) pay[r4.x * BIN_CAP + s] = make_int2(c4.x, __float_as_int(v4.x));
                s = atomicAdd(&cnt[r4.y], 1); if (s < BIN_CAP) pay[r4.y * BIN_CAP + s] = make_int2(c4.y, __float_as_int(v4.y));
                s = atomicAdd(&cnt[r4.z], 1); if (s < BIN_CAP) pay[r4.z * BIN_CAP + s] = make_int2(c4.z, __float_as_int(v4.z));
                s = atomicAdd(&cnt[r4.w], 1); if (s < BIN_CAP) pay[r4.w * BIN_CAP + s] = make_int2(c4.w, __float_as_int(v4.w));
            } else {
                for (int e = e0; e < N_EDGES; ++e) {
                    const int r = rows[e];
                    const int s = atomicAdd(&cnt[r], 1);
                    if (s < BIN_CAP) pay[r * BIN_CAP + s] = make_int2(cols[e], __float_as_int(vals[e]));
                }
            }
        }
    }

    __threadfence();
    grid.sync();

    // ---------------- phase 2: per-row gather-reduce ----------------
    const int lane = tid & 63;
    for (int g = blockIdx.x; g < (N_NODES + 3) / 4; g += gridDim.x) {
        const int row = g * 4 + (tid >> 6);
        if (row >= N_NODES) continue;
        const int n = min(cnt[row], BIN_CAP);
        int2 p = make_int2(0, 0);
        if (lane < n) p = pay[(long)row * BIN_CAP + lane];
        float acc = bias[lane];
        int k = 0;
        for (; k + 8 <= n; k += 8) {
            float gg[8], vv[8];
            #pragma unroll
            for (int j = 0; j < 8; ++j) {
                const int c = __shfl(p.x, k + j, 64);
                vv[j] = __int_as_float(__shfl(p.y, k + j, 64));
                gg[j] = support[(long)c * OUT_SIZE + lane];
            }
            #pragma unroll
            for (int j = 0; j < 8; ++j) acc += gg[j] * vv[j];
        }
        for (; k < n; ++k) {
            const int c = __shfl(p.x, k, 64);
            const float v = __int_as_float(__shfl(p.y, k, 64));
            acc += support[(long)c * OUT_SIZE + lane] * v;
        }
        out[(long)row * OUT_SIZE + lane] = acc;
    }
}

// =========================================================================
// Fallback path (R6 structure): memset + fused_gemm_bin + reduce_rows_pay
// =========================================================================
#define G_GEMM NGEMM
#define G_BIN  ((N_EDGES / 4 + 255) / 256)

__global__ __launch_bounds__(256) void fused_gemm_bin(
        const float* __restrict__ x, const float* __restrict__ w,
        float* __restrict__ support,
        const int* __restrict__ rows, const int* __restrict__ cols,
        const float* __restrict__ vals,
        int* __restrict__ cnt, int2* __restrict__ pay) {
    __shared__ float xs[BM][KPAD];
    __shared__ float wt[4][OUT_SIZE][32];
    const int tid = threadIdx.x;

    if (blockIdx.x < G_GEMM) {
        const int row0 = blockIdx.x * BM;
        #pragma unroll
        for (int i = 0; i < 8; ++i) {
            const int f  = tid + 256 * i;
            const int k  = f >> 4;
            const int c0 = (f & 15) << 2;
            const float4 wv = ((const float4*)w)[f];
            const int kk = k & 31;
            const int sw = (((kk >> 2) ^ (f & 7)) << 2) + (kk & 3);
            wt[k >> 5][c0 + 0][sw] = wv.x;
            wt[k >> 5][c0 + 1][sw] = wv.y;
            wt[k >> 5][c0 + 2][sw] = wv.z;
            wt[k >> 5][c0 + 3][sw] = wv.w;
        }
        float4 xreg[4];
        #pragma unroll
        for (int i = 0; i < 4; ++i) {
            const int f = tid + 256 * i;
            int r = row0 + (f >> 3);
            if (r >= N_NODES) r = N_NODES - 1;
            xreg[i] = *(const float4*)(x + (long)r * IN_SIZE + ((f & 7) << 2));
        }
        const int rg = tid & 15;
        const int c0r = (tid >> 4) << 2;
        const int m7  = (tid >> 4) & 7;
        float4 acc[8];
        #pragma unroll
        for (int i = 0; i < 8; ++i) acc[i] = make_float4(0.f, 0.f, 0.f, 0.f);
        for (int kc = 0; kc < 4; ++kc) {
            __syncthreads();
            #pragma unroll
            for (int i = 0; i < 4; ++i) {
                const int f = tid + 256 * i;
                *(float4*)&xs[f >> 3][(f & 7) << 2] = xreg[i];
            }
            __syncthreads();
            if (kc < 3) {
                #pragma unroll
                for (int i = 0; i < 4; ++i) {
                    const int f = tid + 256 * i;
                    int r = row0 + (f >> 3);
                    if (r >= N_NODES) r = N_NODES - 1;
                    xreg[i] = *(const float4*)(x + (long)r * IN_SIZE + (kc + 1) * KC + ((f & 7) << 2));
                }
            }
            #pragma unroll
            for (int k4 = 0; k4 < 8; ++k4) {
                const int so = (k4 ^ m7) << 2;
                const float4 w0 = *(const float4*)&wt[kc][c0r + 0][so];
                const float4 w1 = *(const float4*)&wt[kc][c0r + 1][so];
                const float4 w2 = *(const float4*)&wt[kc][c0r + 2][so];
                const float4 w3 = *(const float4*)&wt[kc][c0r + 3][so];
                #pragma unroll
                for (int i = 0; i < 8; ++i) {
                    const float4 xv = *(const float4*)&xs[rg + (i << 4)][k4 << 2];
                    acc[i].x += xv.x * w0.x + xv.y * w0.y + xv.z * w0.z + xv.w * w0.w;
                    acc[i].y += xv.x * w1.x + xv.y * w1.y + xv.z * w1.z + xv.w * w1.w;
                    acc[i].z += xv.x * w2.x + xv.y * w2.y + xv.z * w2.z + xv.w * w2.w;
                    acc[i].w += xv.x * w3.x + xv.y * w3.y + xv.z * w3.z + xv.w * w3.w;
                }
            }
        }
        #pragma unroll
        for (int i = 0; i < 8; ++i) {
            const int r = row0 + rg + (i << 4);
            if (r < N_NODES)
                *(float4*)(support + (long)r * OUT_SIZE + c0r) = acc[i];
        }
    } else {
        const int i  = (blockIdx.x - G_GEMM) * 256 + tid;
        const int e0 = i * 4;
        if (e0 + 4 <= N_EDGES) {
            const int4   r4 = ((const int4*)rows)[i];
            const int4   c4 = ((const int4*)cols)[i];
            const float4 v4 = ((const float4*)vals)[i];
            int s;
            s = atomicAdd(&cnt[r4.x], 1); if (s < BIN_CAP) pay[r4.x * BIN_CAP + s] = make_int2(c4.x, __float_as_int(v4.x));
            s = atomicAdd(&cnt[r4.y], 1); if (s < BIN_CAP) pay[r4.y * BIN_CAP + s] = make_int2(c4.y, __float_as_int(v4.y));
            s = atomicAdd(&cnt[r4.z], 1); if (s < BIN_CAP) pay[r4.z * BIN_CAP + s] = make_int2(c4.z, __float_as_int(v4.z));
            s = atomicAdd(&cnt[r4.w], 1); if (s < BIN_CAP) pay[r4.w * BIN_CAP + s] = make_int2(c4.w, __float_as_int(v4.w));
        } else {
            for (int e = e0; e < N_EDGES; ++e) {
                const int r = rows[e];
                const int s = atomicAdd(&cnt[r], 1);
                if (s < BIN_CAP) pay[r * BIN_CAP + s] = make_int2(cols[e], __float_as_int(vals[e]));
            }
        }
    }
}

__global__ __launch_bounds__(256) void reduce_rows_pay(const float* __restrict__ support,
                                                       const int* __restrict__ cnt,
                                                       const int2* __restrict__ pay,
                                                       const float* __restrict__ bias,
                                                       float* __restrict__ out) {
    const int tid  = threadIdx.x;
    const int lane = tid & 63;
    const int row  = blockIdx.x * 4 + (tid >> 6);
    if (row >= N_NODES) return;
    const int n = min(cnt[row], BIN_CAP);
    int2 p = make_int2(0, 0);
    if (lane < n) p = pay[(long)row * BIN_CAP + lane];
    float acc = bias[lane];
    int k = 0;
    for (; k + 8 <= n; k += 8) {
        float g[8], v[8];
        #pragma unroll
        for (int j = 0; j < 8; ++j) {
            const int c = __shfl(p.x, k + j, 64);
            v[j] = __int_as_float(__shfl(p.y, k + j, 64));
            g[j] = support[(long)c * OUT_SIZE + lane];
        }
        #pragma unroll
        for (int j = 0; j < 8; ++j) acc += g[j] * v[j];
    }
    for (; k < n; ++k) {
        const int c = __shfl(p.x, k, 64);
        const float v = __int_as_float(__shfl(p.y, k, 64));
        acc += support[(long)c * OUT_SIZE + lane] * v;
    }
    out[(long)row * OUT_SIZE + lane] = acc;
}

// =========================================================================
extern "C" void kernel_launch(void* const* d_in, const int* in_sizes, int n_in,
                              void* d_out, int out_size, void* d_ws, size_t ws_size,
                              hipStream_t stream) {
    const float* x      = (const float*)d_in[0];
    const int*   rows   = (const int*)d_in[1];
    const int*   cols   = (const int*)d_in[2];
    const float* vals   = (const float*)d_in[3];
    const float* weight = (const float*)d_in[4];
    const float* bias   = (const float*)d_in[5];
    float*       out    = (float*)d_out;

    const size_t support_bytes = (size_t)N_NODES * OUT_SIZE * sizeof(float); // 12.8 MB
    const size_t cnt_bytes     = (size_t)N_NODES * sizeof(int);              // 0.2 MB
    const size_t pay_bytes     = (size_t)N_NODES * BIN_CAP * sizeof(int2);   // 25.6 MB

    float* support = (float*)d_ws;
    int*   cnt     = (int*)((char*)d_ws + support_bytes);
    int2*  pay     = (int2*)((char*)d_ws + support_bytes + cnt_bytes);
    int*   task    = (int*)((char*)d_ws + support_bytes + cnt_bytes + pay_bytes);

    if (ws_size >= support_bytes + cnt_bytes + pay_bytes + 256) {
        // ---- cooperative single-dispatch path (registers uncapped) ----
        int occ = 0;
        if (hipOccupancyMaxActiveBlocksPerMultiprocessor(&occ, gcn_coop, 256, 0)
                == hipSuccess && occ > 0) {
            if (occ > 4) occ = 4;
            int nblocks = occ * 256;            // 256 CUs on MI355X
            void* args[] = {(void*)&x, (void*)&weight, (void*)&rows, (void*)&cols,
                            (void*)&vals, (void*)&bias, (void*)&support, (void*)&cnt,
                            (void*)&pay, (void*)&task, (void*)&out};
            if (hipLaunchCooperativeKernel((void*)gcn_coop, dim3(nblocks), dim3(256),
                                           args, 0, stream) == hipSuccess)
                return;
        }
        // ---- fallback: R6 three-dispatch path ----
        hipMemsetAsync(cnt, 0, cnt_bytes, stream);
        fused_gemm_bin<<<G_GEMM + G_BIN, 256, 0, stream>>>(x, weight, support,
                                                           rows, cols, vals, cnt, pay);
        reduce_rows_pay<<<(N_NODES + 3) / 4, 256, 0, stream>>>(support, cnt, pay, bias, out);
        return;
    }

    hipMemsetAsync(cnt, 0, cnt_bytes, stream);
    fused_gemm_bin<<<G_GEMM + G_BIN, 256, 0, stream>>>(x, weight, support,
                                                       rows, cols, vals, cnt, pay);
    reduce_rows_pay<<<(N_NODES + 3) / 4, 256, 0, stream>>>(support, cnt, pay, bias, out);
}